// Round 4
// baseline (94.040 us; speedup 1.0000x reference)
//
#include <hip/hip_runtime.h>

// Problem constants (from reference): B=256, IN=1024, OUT=1024, fp32.
#define BB   256
#define IN_  1024
#define OUTN 1024

// Geometry (round-9): 16(b) x 16(o) tile, 256 threads (4 waves), 2x2 (b,o)
// micro-tile per thread, 4-way K-split with K-quarter == WAVE ID (h=tid>>6).
//
// Model (postdicts rounds 5/6 exactly): ds_read_b128 costs ~12 cyc of
// CU-shared LDS pipe regardless of broadcast (m134). At 1 cell/thread
// (2 reads per 4 per-lane elems, 8 B/elem) the kernel needs 98k cyc/CU
// = 41 us -- measured 41.5/44.0, occupancy-insensitive. The 2x2 micro-tile
// amortizes 4 reads across 16 per-lane elements (4 B/elem) -> 49k cyc/CU
// ~ 20.5 us floor; trans pipe (33k cyc/SIMD = 13.7 us) stays subordinate.
//
// De-risking after two failed micro-tile attempts (r7: LDS epilogue +
// pk-asm; r8: shuffle epilogue + pk-asm -- both logic-verified yet wrong):
// NO inline asm in the inner loop (scalar FP: VALU demand 24.6k cyc/SIMD
// = 10.2 us < LDS floor, so pk asm bought nothing), direct array indexing,
// plain __syncthreads() only, prefetch issued after the post-write barrier
// (covered by a full compute stage), epilogue structurally identical to
// the PASSING round-6 scratch pattern, scalar output stores.
#define TB  16
#define TO  16
#define KC  256          // i per LDS stage (4 stages)
#define NS  (IN_ / KC)
#define PAD 4            // row stride 260 floats = 1040 B (16B-aligned)

#define LOG2E 1.4426950408889634f

typedef float v4f __attribute__((ext_vector_type(4)));

// leaky_clamp(v,0,1,0.1) == med3(v, 0.1*v, 0.9 + 0.1*v). Proven r0-r6.
__device__ __forceinline__ float leaky_clamp01(float v) {
    return __builtin_amdgcn_fmed3f(v, 0.1f * v, fmaf(0.1f, v, 0.9f));
}

// Numerics (proven r0-r6): |tau*z| <= ~0.9, so no max-subtraction pass:
// d=sum(exp2(t)), n=sum(exp2(t)*t) with t=(tau*log2e*x)*aw;
// s = n / (d * tau * log2e). The 4-way K-split only repartitions the
// all-positive-d sums.
__global__ __launch_bounds__(256, 4)
void esm_fused_kernel(const float* __restrict__ x,
                      const float* __restrict__ w,
                      const float* __restrict__ log_tau,
                      float* __restrict__ out) {
    __shared__ float xs[TB][KC + PAD];   // 16 x 260 floats = 16.6 KB
    __shared__ float wls[TO][KC + PAD];  // 16 x 260 floats = 16.6 KB

    const int tid = threadIdx.x;        // 0..255
    const int bid = blockIdx.x;
    // ot in low bits: one XCD's resident blocks span few o-tiles -> w
    // footprint fits per-XCD L2; FETCH_SIZE measured ~6.2 MB (no overfetch).
    const int bt = bid >> 6;            // 0..15
    const int ot = bid & 63;            // 0..63
    const int b0 = bt * TB;
    const int o0 = ot * TO;

    const float scale = __expf(log_tau[0]) * LOG2E;  // tau * log2(e)

    // h = tid>>6 = wave id = K-quarter: thread reads i in {16m+4h..16m+4h+3}.
    // cell = tid&63 -> (ty,tx) in 8x8 pair-grid; thread owns output cells
    // (2ty+r, 2tx+c), r,c in {0,1}.
    // Wave-level LDS pattern (h uniform per wave): x-reads hit 8 distinct
    // addresses (8-lane broadcast), rows 2ty{+1}: banks (8ty+4r)&31 ->
    // 2-way alias max (free, m136). w-reads identical structure. Expect
    // SQ_LDS_BANK_CONFLICT ~ 0.
    const int h    = tid >> 6;          // 0..3 (== wave id)
    const int cell = tid & 63;
    const int tx   = cell & 7;          // o-pair index
    const int ty   = cell >> 3;         // b-pair index
    const int ih   = h << 2;            // slot within each 16-i group

    // Staging decode: f = tid + t*256 -> row = (tid>>6)+4t, i4 = (tid&63)*4.
    // 64-lane clusters read 1 KB contiguous (coalesced); LDS writes are
    // contiguous b128 (conflict-free). Identical structure to r5 (passed).
    const int srow = tid >> 6;          // 0..3
    const int si4  = (tid & 63) << 2;   // 0..252

    // Prefetch stage 0 into registers (8 float4 = 32 VGPRs).
    float4 rx[4], rw[4];
    #pragma unroll
    for (int t = 0; t < 4; ++t) {
        const int row = srow + t * 4;
        rx[t] = *(const float4*)&x[(size_t)(b0 + row) * IN_ + si4];
        rw[t] = *(const float4*)&w[(size_t)(o0 + row) * IN_ + si4];
    }

    float d00 = 0.f, d01 = 0.f, d10 = 0.f, d11 = 0.f;
    float n00 = 0.f, n01 = 0.f, n10 = 0.f, n11 = 0.f;

    #pragma unroll
    for (int s = 0; s < NS; ++s) {
        if (s) __syncthreads();   // stage s-1 readers done before overwrite
        // Store prefetched registers to LDS (x pre-scaled, w pre-clamped).
        // The vmcnt wait for rx/rw lands here, covered by compute of s-1.
        #pragma unroll
        for (int t = 0; t < 4; ++t) {
            const int row = srow + t * 4;
            const float4 xv = rx[t];
            float4 xo;
            xo.x = xv.x * scale; xo.y = xv.y * scale;
            xo.z = xv.z * scale; xo.w = xv.w * scale;
            *(float4*)&xs[row][si4] = xo;
            const float4 wv = rw[t];
            float4 wo;
            wo.x = leaky_clamp01(wv.x); wo.y = leaky_clamp01(wv.y);
            wo.z = leaky_clamp01(wv.z); wo.w = leaky_clamp01(wv.w);
            *(float4*)&wls[row][si4] = wo;
        }
        __syncthreads();          // stage s LDS data visible
        // Prefetch stage s+1 AFTER the barrier: loads fly during compute-s;
        // no custom barrier needed to keep them in flight.
        if (s + 1 < NS) {
            const int i0n = (s + 1) * KC;
            #pragma unroll
            for (int t = 0; t < 4; ++t) {
                const int row = srow + t * 4;
                rx[t] = *(const float4*)&x[(size_t)(b0 + row) * IN_ + i0n + si4];
                rw[t] = *(const float4*)&w[(size_t)(o0 + row) * IN_ + i0n + si4];
            }
        }

        // Inner: per 16-i group, thread takes its 4-i slot (ih) in 2 x-rows
        // and 2 w-rows: 4 ds_read_b128 -> 16 elements (4 B LDS return per
        // element). All arithmetic is plain scalar fp32 (compiler-scheduled);
        // 16 mul + 16 exp2 + 16 add + 16 fma per group.
        #pragma unroll 4
        for (int m = 0; m < KC / 16; ++m) {
            const int ib = 16 * m + ih;
            const v4f xa0 = *(const v4f*)&xs[2 * ty][ib];
            const v4f xa1 = *(const v4f*)&xs[2 * ty + 1][ib];
            const v4f wa0 = *(const v4f*)&wls[2 * tx][ib];
            const v4f wa1 = *(const v4f*)&wls[2 * tx + 1][ib];
            #pragma unroll
            for (int k = 0; k < 4; ++k) {
                const float t00 = xa0[k] * wa0[k];
                const float t01 = xa0[k] * wa1[k];
                const float t10 = xa1[k] * wa0[k];
                const float t11 = xa1[k] * wa1[k];
                const float e00 = __builtin_amdgcn_exp2f(t00);
                const float e01 = __builtin_amdgcn_exp2f(t01);
                const float e10 = __builtin_amdgcn_exp2f(t10);
                const float e11 = __builtin_amdgcn_exp2f(t11);
                d00 += e00; d01 += e01; d10 += e10; d11 += e11;
                n00 = fmaf(e00, t00, n00);
                n01 = fmaf(e01, t01, n01);
                n10 = fmaf(e10, t10, n10);
                n11 = fmaf(e11, t11, n11);
            }
        }
    }

    // 4-way K-quarter reduction through reused LDS (round-6's proven scratch
    // pattern, widened). Layout sd[h*256 + co], co = output cell id; every
    // (h,co) slot written by exactly one thread. 2 KB per array.
    __syncthreads();            // all inner-loop LDS reads complete
    float* sd = &xs[0][0];
    float* sn = &wls[0][0];
    const int co00 = (2 * ty) * 16 + 2 * tx;   // cell (2ty, 2tx)
    sd[(h << 8) + co00]      = d00;
    sd[(h << 8) + co00 + 1]  = d01;
    sd[(h << 8) + co00 + 16] = d10;
    sd[(h << 8) + co00 + 17] = d11;
    sn[(h << 8) + co00]      = n00;
    sn[(h << 8) + co00 + 1]  = n01;
    sn[(h << 8) + co00 + 16] = n10;
    sn[(h << 8) + co00 + 17] = n11;
    __syncthreads();
    if (h == 0) {
        // Wave 0's 64 threads finalize their own 4 cells (all 256 covered).
        float dt00 = 0.f, dt01 = 0.f, dt10 = 0.f, dt11 = 0.f;
        float nt00 = 0.f, nt01 = 0.f, nt10 = 0.f, nt11 = 0.f;
        #pragma unroll
        for (int hh = 0; hh < 4; ++hh) {
            const int base = (hh << 8) + co00;
            dt00 += sd[base];      dt01 += sd[base + 1];
            dt10 += sd[base + 16]; dt11 += sd[base + 17];
            nt00 += sn[base];      nt01 += sn[base + 1];
            nt10 += sn[base + 16]; nt11 += sn[base + 17];
        }
        const size_t r0o = (size_t)(b0 + 2 * ty) * OUTN + o0 + 2 * tx;
        const size_t r1o = (size_t)(b0 + 2 * ty + 1) * OUTN + o0 + 2 * tx;
        out[r0o]     = nt00 / (dt00 * scale);
        out[r0o + 1] = nt01 / (dt01 * scale);
        out[r1o]     = nt10 / (dt10 * scale);
        out[r1o + 1] = nt11 / (dt11 * scale);
    }
}

extern "C" void kernel_launch(void* const* d_in, const int* in_sizes, int n_in,
                              void* d_out, int out_size, void* d_ws, size_t ws_size,
                              hipStream_t stream) {
    const float* x  = (const float*)d_in[0];   // (256, 1024)
    const float* w  = (const float*)d_in[1];   // (1024, 1024)
    const float* lt = (const float*)d_in[2];   // scalar log_tau
    float* out = (float*)d_out;                // (256, 1024)

    esm_fused_kernel<<<(BB / TB) * (OUTN / TO), 256, 0, stream>>>(x, w, lt, out);
}